// Round 1
// baseline (2202.074 us; speedup 1.0000x reference)
//
#include <hip/hip_runtime.h>
#include <hip/hip_bf16.h>

// BeamDecoder: greedy CVRP-style decode.
// s_i(step) = c*( G[last,i] + (load/cap)*u_i )   (v==0 since bq==0; folded)
//
// R10: the per-step DEPENDENT global load of the 128-candidate row dominated
// (per-XCD L2 is invalidated at dispatch boundaries, so every step paid
// LLC/HBM latency ~600-900cyc + ~350cyc line service; measured 1714 cyc/step
// vs ~400 cyc of eval). Fix: certified 15-entry candidate lists packed into
// LDS (gfx950 has 160 KiB LDS; 2048 rows x 15 x u32 = 120 KB). Packing:
// top-21 bits of the monotonic key of g | 11-bit idx, so ghat <= g <=
// ghat + 0.0313 (prep flags rows whose top-15 |g| >= 128 -> exact path).
// Tier-1 selects by that = fmaf(u, lr, ghat) with a top-2 DPP reduce and
// certifies only when (winner - runnerup) > 0.0625 (so the exact argmax
// index is provably identical; exact ties always fail margin -> exact path)
// AND winner > thr15 + lr*umax + 0.5 (beats all outside nodes - same
// B-test soundness as R8/R9). Tier-2 = R9-verbatim 128-list path with its
// row load issued speculatively at step start (3-deep register rotation so
// reissue never WAR-stalls). Tier-3 = R5-verbatim full-row scan.
// Scores exact via the unchanged deferred pass.

#define NN 2048
#define HH 1024
#define TSTEPS (NN + NN / 8)   // 2304 (divisible by 3 for the 3x unroll)
#define TILE 64
#define KT 16
#define KCAND 128
#define KL 15

// ---------------- pack Wq[:, :H] into ld=1024 buffer ----------------
__global__ __launch_bounds__(256) void prep_wqh(const float* __restrict__ Wq,
                                                float* __restrict__ Wqh) {
  int id = blockIdx.x * 256 + threadIdx.x;
  int r = id >> 10, c = id & 1023;
  Wqh[id] = Wq[r * (HH + 2) + c];
}

// ---------------- NT GEMM: C[M,N] = A[M,K] @ B[N,K]^T (+ bias[n]) ----------------
__global__ __launch_bounds__(256) void gemm_nt(const float* __restrict__ A, int lda,
                                               const float* __restrict__ B, int ldb,
                                               float* __restrict__ C, int ldc,
                                               int K, const float* __restrict__ bias) {
  __shared__ float As[KT][TILE + 4];
  __shared__ float Bs[KT][TILE + 4];
  const int i0 = blockIdx.y * TILE;
  const int j0 = blockIdx.x * TILE;
  const int t = threadIdx.x;
  const int srow = t >> 2, sq = t & 3;
  const int tx = t & 15, ty = t >> 4;
  float acc[4][4] = {};
  for (int k0 = 0; k0 < K; k0 += KT) {
    float4 av = *(const float4*)&A[(size_t)(i0 + srow) * lda + k0 + sq * 4];
    float4 bv = *(const float4*)&B[(size_t)(j0 + srow) * ldb + k0 + sq * 4];
    __syncthreads();
    As[sq * 4 + 0][srow] = av.x; As[sq * 4 + 1][srow] = av.y;
    As[sq * 4 + 2][srow] = av.z; As[sq * 4 + 3][srow] = av.w;
    Bs[sq * 4 + 0][srow] = bv.x; Bs[sq * 4 + 1][srow] = bv.y;
    Bs[sq * 4 + 2][srow] = bv.z; Bs[sq * 4 + 3][srow] = bv.w;
    __syncthreads();
#pragma unroll
    for (int k = 0; k < KT; ++k) {
      float4 a4 = *(const float4*)&As[k][ty * 4];
      float4 b4 = *(const float4*)&Bs[k][tx * 4];
      float a[4] = {a4.x, a4.y, a4.z, a4.w};
      float b[4] = {b4.x, b4.y, b4.z, b4.w};
#pragma unroll
      for (int m = 0; m < 4; ++m)
#pragma unroll
        for (int n = 0; n < 4; ++n) acc[m][n] = fmaf(a[m], b[n], acc[m][n]);
    }
  }
  float bb[4] = {0.f, 0.f, 0.f, 0.f};
  if (bias) {
#pragma unroll
    for (int n = 0; n < 4; ++n) bb[n] = bias[j0 + tx * 4 + n];
  }
#pragma unroll
  for (int m = 0; m < 4; ++m) {
    float4 st = {acc[m][0] + bb[0], acc[m][1] + bb[1], acc[m][2] + bb[2], acc[m][3] + bb[3]};
    *(float4*)&C[(size_t)(i0 + ty * 4 + m) * ldc + j0 + tx * 4] = st;
  }
}

// ---------------- u_i = K_i . Wq[:,H], v_i = K_i . bq  (one wave per row) ---------
__global__ __launch_bounds__(64) void uv_k(const float* __restrict__ Kmat,
                                           const float* __restrict__ Wq,
                                           const float* __restrict__ bq,
                                           float* __restrict__ u, float* __restrict__ v) {
  int i = blockIdx.x;
  int lane = threadIdx.x;
  float su = 0.f, sv = 0.f;
#pragma unroll
  for (int m = 0; m < HH / 64; ++m) {
    int j = lane + 64 * m;
    float kv = Kmat[(size_t)i * HH + j];
    su = fmaf(kv, Wq[(size_t)j * (HH + 2) + HH], su);
    sv = fmaf(kv, bq[j], sv);
  }
#pragma unroll
  for (int off = 32; off; off >>= 1) {
    su += __shfl_down(su, off, 64);
    sv += __shfl_down(sv, off, 64);
  }
  if (lane == 0) { u[i] = su; v[i] = sv; }
}

// ---------------- umax = max |u| ----------------
__global__ __launch_bounds__(256) void umax_k(const float* __restrict__ u,
                                              float* __restrict__ umaxp) {
  __shared__ float sm[256];
  int t = threadIdx.x;
  float m = 0.f;
  for (int i = t; i < NN; i += 256) m = fmaxf(m, fabsf(u[i]));
  sm[t] = m;
  __syncthreads();
  for (int s = 128; s; s >>= 1) {
    if (t < s) sm[t] = fmaxf(sm[t], sm[t + s]);
    __syncthreads();
  }
  if (t == 0) *umaxp = sm[0];
}

// ---------------- per-row exact top-K by g: 4-pass radix-select ----------------
__device__ __forceinline__ unsigned f2key(float f) {
  unsigned x = __float_as_uint(f);
  return x ^ ((x >> 31) ? 0xFFFFFFFFu : 0x80000000u);  // monotonic asc mapping
}
__device__ __forceinline__ float key2f(unsigned k) {
  unsigned x = (k & 0x80000000u) ? (k ^ 0x80000000u) : ~k;
  return __uint_as_float(x);
}
// Produces: cand[row][0..127] exact top-128 (value,idx), thr[row] = exact
// 128th-largest value; pc16[row][0..14] packed top-15 (key&~0x7FF | idx),
// thr16[row] = exact 15th-largest value (+inf if any of the 15 has |g|>=128,
// which disables tier-1 for that row so the packing error bound holds).
__global__ __launch_bounds__(256) void prep_cand(const float* __restrict__ GT,
                                                 uint2* __restrict__ cand,
                                                 float* __restrict__ thr,
                                                 unsigned* __restrict__ pc16,
                                                 float* __restrict__ thr16) {
  __shared__ float rowv[NN];
  __shared__ int hist[256];
  __shared__ unsigned c128k[KCAND];
  __shared__ int c128i[KCAND];
  __shared__ int s_d, s_need, s_gt, s_eq, s_gt2, s_eq2, s_flag;
  const int row = blockIdx.x, t = threadIdx.x;
  for (int i = t; i < NN; i += 256) rowv[i] = GT[(size_t)row * NN + i];
  __syncthreads();
  unsigned prefix = 0;
  int need = KCAND;
  for (int pass = 0; pass < 4; ++pass) {
    hist[t] = 0;
    __syncthreads();
    const int shift = 24 - 8 * pass;
    for (int i = t; i < NN; i += 256) {
      unsigned k = f2key(rowv[i]);
      if (pass == 0 || (k >> (shift + 8)) == (prefix >> (shift + 8)))
        atomicAdd(&hist[(k >> shift) & 0xFF], 1);
    }
    __syncthreads();
    if (t == 0) {
      int cum = 0, d = 255;
      for (; d > 0; --d) {
        if (cum + hist[d] >= need) break;
        cum += hist[d];
      }
      s_d = d;
      s_need = need - cum;
    }
    __syncthreads();
    prefix |= ((unsigned)s_d) << shift;
    need = s_need;
    __syncthreads();
  }
  const unsigned thrk = prefix;  // exact KCAND-th largest key
  if (t == 0) { s_gt = 0; s_eq = 0; thr[row] = key2f(thrk); }
  __syncthreads();
  for (int i = t; i < NN; i += 256) {
    unsigned k = f2key(rowv[i]);
    if (k > thrk) {
      int p = atomicAdd(&s_gt, 1);
      cand[(size_t)row * KCAND + p] = make_uint2(__float_as_uint(rowv[i]), (unsigned)i);
      c128k[p] = k;
      c128i[p] = i;
    }
  }
  __syncthreads();
  const int cgt = s_gt;
  for (int i = t; i < NN; i += 256) {
    if (f2key(rowv[i]) == thrk) {
      int p = atomicAdd(&s_eq, 1);
      if (p < KCAND - cgt) {
        cand[(size_t)row * KCAND + cgt + p] = make_uint2(__float_as_uint(rowv[i]), (unsigned)i);
        c128k[cgt + p] = thrk;
        c128i[cgt + p] = i;
      }
    }
  }
  __syncthreads();
  // ---- exact 15th-largest among the 128 keys (multiset top-15 of the row
  //      equals multiset top-15 of the 128-list; idx fill at ties arbitrary,
  //      soundness comes from the B-test against thr16)
  unsigned pfx2 = 0;
  need = KL;
  for (int pass = 0; pass < 4; ++pass) {
    hist[t] = 0;
    __syncthreads();
    const int shift = 24 - 8 * pass;
    for (int i = t; i < KCAND; i += 256) {
      unsigned k = c128k[i];
      if (pass == 0 || (k >> (shift + 8)) == (pfx2 >> (shift + 8)))
        atomicAdd(&hist[(k >> shift) & 0xFF], 1);
    }
    __syncthreads();
    if (t == 0) {
      int cum = 0, d = 255;
      for (; d > 0; --d) {
        if (cum + hist[d] >= need) break;
        cum += hist[d];
      }
      s_d = d;
      s_need = need - cum;
    }
    __syncthreads();
    pfx2 |= ((unsigned)s_d) << shift;
    need = s_need;
    __syncthreads();
  }
  const unsigned thrk15 = pfx2;
  if (t == 0) { s_gt2 = 0; s_eq2 = 0; s_flag = 0; }
  __syncthreads();
  for (int i = t; i < KCAND; i += 256) {
    if (c128k[i] > thrk15) {
      int p = atomicAdd(&s_gt2, 1);
      pc16[(size_t)row * KL + p] = (c128k[i] & 0xFFFFF800u) | (unsigned)c128i[i];
      if (fabsf(key2f(c128k[i])) >= 128.0f) s_flag = 1;
    }
  }
  __syncthreads();
  const int cgt2 = s_gt2;
  for (int i = t; i < KCAND; i += 256) {
    if (c128k[i] == thrk15) {
      int p = atomicAdd(&s_eq2, 1);
      if (p < KL - cgt2)
        pc16[(size_t)row * KL + cgt2 + p] = (thrk15 & 0xFFFFF800u) | (unsigned)c128i[i];
    }
  }
  if (t == 0 && fabsf(key2f(thrk15)) >= 128.0f) s_flag = 1;
  __syncthreads();
  if (t == 0) thr16[row] = s_flag ? __builtin_inff() : key2f(thrk15);
}

// ---------------- LLC pre-warm for the tier-2 lists ------------------------------
__global__ __launch_bounds__(256) void warm_k(const float* __restrict__ a, int n,
                                              const float* __restrict__ b, int m,
                                              float* __restrict__ sink) {
  float s = 0.f;
  const float4* a4 = (const float4*)a;
  for (int i = threadIdx.x; i < n / 4; i += 256) {
    float4 x = a4[i];
    s += x.x + x.y + x.z + x.w;
  }
  for (int i = threadIdx.x; i < m; i += 256) s += b[i];
  if (s == 1.2345e-30f) sink[blockIdx.x] = s;  // never true; keeps loads alive
}

// DPP merge of (bv,bi): max value, smallest index on ties. Invalid lanes get
// (-inf, INT_MAX).
#define DPP_MERGE2(CTRL)                                                      \
  {                                                                           \
    int ovb = __builtin_amdgcn_update_dpp(                                    \
        (int)0xFF800000, __float_as_int(bv), (CTRL), 0xf, 0xf, false);        \
    int oib = __builtin_amdgcn_update_dpp(                                    \
        0x7fffffff, bi, (CTRL), 0xf, 0xf, false);                             \
    float ov = __int_as_float(ovb);                                           \
    if (ov > bv || (ov == bv && oib < bi)) { bv = ov; bi = oib; }             \
  }

// DPP top-2 merge: (bv1,bi1) = max with min-idx ties; bv2 = exact runner-up
// VALUE of the merged set. The shr1/2/4/8 + bcast15/31 topology merges
// disjoint lane ranges, so lane 63 holds the duplicate-free top-2.
#define DPP_TOP2(CTRL)                                                        \
  {                                                                           \
    int ovb = __builtin_amdgcn_update_dpp(                                    \
        (int)0xFF800000, __float_as_int(bv1), (CTRL), 0xf, 0xf, false);       \
    int oib = __builtin_amdgcn_update_dpp(                                    \
        0x7fffffff, bi1, (CTRL), 0xf, 0xf, false);                            \
    int ov2b = __builtin_amdgcn_update_dpp(                                   \
        (int)0xFF800000, __float_as_int(bv2), (CTRL), 0xf, 0xf, false);       \
    float ov1 = __int_as_float(ovb);                                          \
    float ov2 = __int_as_float(ov2b);                                         \
    float lose = fminf(bv1, ov1);                                             \
    if (ov1 > bv1 || (ov1 == bv1 && oib < bi1)) { bv1 = ov1; bi1 = oib; }     \
    bv2 = fmaxf(fmaxf(bv2, ov2), lose);                                       \
  }

// ---------------- sequential decode: ONE wave ------------------------------------
__global__ __launch_bounds__(64, 1) void decode(const float* __restrict__ GT,
                                                const uint2* __restrict__ cand,
                                                const float* __restrict__ thrp,
                                                const unsigned* __restrict__ pc16,
                                                const float* __restrict__ thr16,
                                                const float* __restrict__ umaxp,
                                                const float* __restrict__ u,
                                                const float* __restrict__ demands,
                                                const int* __restrict__ capp,
                                                const int* __restrict__ depotp,
                                                float* __restrict__ out) {
  __shared__ __align__(16) unsigned s_pc[NN * KL + 64];  // packed tier-1 lists (+pad)
  __shared__ __align__(16) float s_dd[NN];               // demands, +inf when visited
  __shared__ __align__(16) float s_u[NN];                // u_i
  __shared__ __align__(16) float s_thr[NN];              // tier-1 thr15 (+inf sentinel)
  __shared__ __align__(16) float s_lr[TSTEPS];           // lr per step; -1 => score 0
  __shared__ __align__(16) unsigned short s_tour[TSTEPS + 2];

  const int lane = threadIdx.x;
  const int depot = *depotp;
  const float capf = (float)(*capp);
  const float umaxv = *umaxp;
  const float INF = __builtin_inff();
  const float NEGINF = -INF;
  const float C0 = 0.015625f;   // ALPHA / sqrt(HID), exact power of two
  const float MARGIN = 0.5f;    // >> any fp32 rounding in the bound
  const float EGM = 0.0625f;    // > max packing error 0.0313 (|g|<128) + rounding

  for (int i = lane; i < NN; i += 64) {
    s_dd[i] = demands[i];
    s_u[i] = u[i];
    s_thr[i] = thr16[i];
  }
  {
    const uint4* p4 = (const uint4*)pc16;
    uint4* q4 = (uint4*)s_pc;
    for (int i = lane; i < NN * KL / 4; i += 64) q4[i] = p4[i];
  }
  if (lane == 0) {
    s_dd[depot] = INF;  // depot starts visited
    s_tour[0] = (unsigned short)depot;
  }
  // single wave: per-wave LDS ordering suffices; no barrier needed

  int done = 0, ntaken = 0, lasts = depot;
  float load = capf;
  float lr = load / capf;  // same fp32 division as reference
  int step = 0;
  uint4 cc0, cc1, cc2;     // 3-deep rotated speculative tier-2 row regs
  float th0, th1, th2;

#define STEP_ONE(CC, TH)                                                        \
  {                                                                             \
    if (done) goto FLUSH;                                                       \
    const int row = lasts;                                                      \
    /* speculative tier-2 row load: used only on tier-1 miss; 3-deep rotation   \
       means the reissue 3 steps later never WAR-stalls */                      \
    CC = ((const uint4*)(cand + (size_t)row * KCAND))[lane];                    \
    TH = thrp[row];                                                             \
    /* ---- tier-1: 15 packed candidates from LDS */                            \
    unsigned pw = s_pc[row * KL + lane];                                        \
    float thr1 = s_thr[row];                                                    \
    int i1x = (int)(pw & 0x7FFu);                                               \
    float g1 = key2f(pw & 0xFFFFF800u);   /* ghat <= g <= ghat + 0.0313 */      \
    float d1 = s_dd[i1x];                                                       \
    float su1 = s_u[i1x];                                                       \
    float t1 = fmaf(su1, lr, g1);                                               \
    bool act = (lane < KL) && (d1 <= load);                                     \
    float bv1 = act ? t1 : NEGINF;                                              \
    int bi1 = act ? i1x : 0x7fffffff;                                           \
    float bv2 = NEGINF;                                                         \
    DPP_TOP2(0x111); DPP_TOP2(0x112); DPP_TOP2(0x114);                          \
    DPP_TOP2(0x118); DPP_TOP2(0x142); DPP_TOP2(0x143);                          \
    float rv1 = __int_as_float(__builtin_amdgcn_readlane(__float_as_int(bv1), 63)); \
    int ri1 = __builtin_amdgcn_readlane(bi1, 63);                               \
    float rv2 = __int_as_float(__builtin_amdgcn_readlane(__float_as_int(bv2), 63)); \
    const float B1 = fmaf(lr, umaxv, thr1) + MARGIN;                            \
    int take, nxt;                                                              \
    if (rv1 > B1 && rv1 > rv2 + EGM) {                                          \
      /* certified: true t_w >= rv1 > rv2+EGM >= any other in-list true t, and  \
         rv1 > B1 beats every node with g <= thr15 (all outside the 15) */      \
      take = 1; nxt = ri1;                                                      \
    } else {                                                                    \
      /* ---- tier-2: exact eval of the 128-candidate list (R9-verbatim) */     \
      float bv = NEGINF;                                                        \
      int bi = 0x7fffffff;                                                      \
      {                                                                         \
        float ga = __uint_as_float(CC.x); int ia = (int)CC.y;                   \
        float gb = __uint_as_float(CC.z); int ib = (int)CC.w;                   \
        float da = s_dd[ia], ua = s_u[ia];                                      \
        float db = s_dd[ib], ub = s_u[ib];                                      \
        float ta = fmaf(ua, lr, ga);                                            \
        float tb = fmaf(ub, lr, gb);                                            \
        if ((da <= load) && (ta > bv || (ta == bv && ia < bi))) { bv = ta; bi = ia; } \
        if ((db <= load) && (tb > bv || (tb == bv && ib < bi))) { bv = tb; bi = ib; } \
      }                                                                         \
      DPP_MERGE2(0x111); DPP_MERGE2(0x112); DPP_MERGE2(0x114);                  \
      DPP_MERGE2(0x118); DPP_MERGE2(0x142); DPP_MERGE2(0x143);                  \
      float rbv = __int_as_float(__builtin_amdgcn_readlane(__float_as_int(bv), 63)); \
      int rbi = __builtin_amdgcn_readlane(bi, 63);                              \
      const float B2 = fmaf(lr, umaxv, TH) + MARGIN;                            \
      if (rbv > B2) {                                                           \
        take = 1; nxt = rbi;                                                    \
      } else {                                                                  \
        /* ---- tier-3: R5-verbatim exact full-row scan */                      \
        const float4* rowp = (const float4*)(GT + (size_t)row * NN);            \
        const float4* dd4 = (const float4*)s_dd;                                \
        const float4* uu4 = (const float4*)s_u;                                 \
        float fv = NEGINF;                                                      \
        int fi = NN;                                                            \
        _Pragma("unroll") for (int r = 0; r < 8; ++r) {                         \
          float4 g4 = rowp[r * 64 + lane];                                      \
          float4 d4v = dd4[r * 64 + lane];                                      \
          float4 u4v = uu4[r * 64 + lane];                                      \
          float gl[4] = {g4.x, g4.y, g4.z, g4.w};                               \
          float dl[4] = {d4v.x, d4v.y, d4v.z, d4v.w};                           \
          float ul[4] = {u4v.x, u4v.y, u4v.z, u4v.w};                           \
          float cv = NEGINF;                                                    \
          int cj = 0;                                                           \
          _Pragma("unroll") for (int j = 0; j < 4; ++j) {                       \
            float tt = fmaf(ul[j], lr, gl[j]);                                  \
            bool feas = (dl[j] <= load);                                        \
            if (feas && tt > cv) { cv = tt; cj = j; }                           \
          }                                                                     \
          if (cv > fv) { fv = cv; fi = 4 * (r * 64 + lane) + cj; }              \
        }                                                                       \
        float bv = fv;                                                          \
        int bi = fi;                                                            \
        DPP_MERGE2(0x111); DPP_MERGE2(0x112); DPP_MERGE2(0x114);                \
        DPP_MERGE2(0x118); DPP_MERGE2(0x142); DPP_MERGE2(0x143);                \
        float fbv = __int_as_float(__builtin_amdgcn_readlane(__float_as_int(bv), 63)); \
        int fbi = __builtin_amdgcn_readlane(bi, 63);                            \
        take = (fbv > NEGINF) ? 1 : 0;                                          \
        nxt = take ? fbi : depot;                                               \
      }                                                                         \
    }                                                                           \
    /* ---- state update + LDS-buffered outputs (identical fp ops to ref) */    \
    if (lane == 0) {                                                            \
      s_tour[1 + step] = (unsigned short)nxt;                                   \
      s_lr[step] = take ? lr : -1.0f;                                           \
    }                                                                           \
    if (take) {                                                                 \
      float dwin = s_dd[nxt];  /* raw demand: feasible => not yet INF */        \
      load = load - dwin;                                                       \
      ntaken++;                                                                 \
      if (lane == 0) s_dd[nxt] = INF;                                           \
    } else {                                                                    \
      load = capf;                                                              \
      if (ntaken == NN - 1) done = 1;                                           \
    }                                                                           \
    lasts = nxt;                                                                \
    lr = load / capf;                                                           \
    ++step;                                                                     \
  }

  for (int s3 = 0; s3 < TSTEPS; s3 += 3) {  // TSTEPS = 2304 = 3*768
    STEP_ONE(cc0, th0)
    STEP_ONE(cc1, th1)
    STEP_ONE(cc2, th2)
  }
FLUSH:
  // ref emits (depot, 0) forever once done
  for (int q = step + lane; q < TSTEPS; q += 64) {
    s_tour[1 + q] = (unsigned short)depot;
    s_lr[q] = -1.0f;
  }
  // ---- flush tour; compute scores exactly in a parallel deferred pass
  for (int i = lane; i <= TSTEPS; i += 64) out[i] = (float)s_tour[i];
  for (int s = lane; s < TSTEPS; s += 64) {
    float lrs = s_lr[s];
    float sc = 0.0f;
    if (lrs >= 0.0f) {
      int lastI = (int)s_tour[s];
      int biI = (int)s_tour[s + 1];
      float g = GT[(size_t)lastI * NN + biI];
      sc = fmaf(s_u[biI], lrs, g) * C0;  // identical expression to R3-R9
    }
    out[1 + TSTEPS + s] = sc;
  }
#undef STEP_ONE
}

extern "C" void kernel_launch(void* const* d_in, const int* in_sizes, int n_in,
                              void* d_out, int out_size, void* d_ws, size_t ws_size,
                              hipStream_t stream) {
  const float* emb     = (const float*)d_in[0];  // [N, H]
  const float* demands = (const float*)d_in[1];  // [N]
  const float* Wq      = (const float*)d_in[2];  // [H, H+2]
  const float* bq      = (const float*)d_in[3];  // [H]
  const float* Wk      = (const float*)d_in[4];  // [H, H]
  const float* bk      = (const float*)d_in[5];  // [H]
  const int* cap       = (const int*)d_in[6];
  const int* depot     = (const int*)d_in[7];
  float* out           = (float*)d_out;          // 2305 tour + 2304 scores, fp32

  char* ws = (char*)d_ws;
  float* Kmat = (float*)(ws);                         // 8 MB  [N,H]
  float* Z    = (float*)(ws + ((size_t)8 << 20));     // 8 MB  [N,H]
  float* GT   = (float*)(ws + ((size_t)16 << 20));    // 16 MB [N,N] row=last, +v
  float* Wqh  = (float*)(ws + ((size_t)32 << 20));    // 4 MB  [H,H]; later = cand+pc16
  float* u    = (float*)(ws + ((size_t)36 << 20));    // 8 KB
  float* v    = (float*)(ws + ((size_t)36 << 20) + 8192);
  float* thr  = (float*)(ws + ((size_t)36 << 20) + 16384);  // 8 KB
  float* umax = (float*)(ws + ((size_t)36 << 20) + 24576);
  float* sink = (float*)(ws + ((size_t)36 << 20) + 32768);  // warm sink (unused)
  uint2* cnd  = (uint2*)Wqh;  // 2 MB = 2048*128*8 B; Wqh dead after Z GEMM
  unsigned* pc16g = (unsigned*)(ws + ((size_t)34 << 20));            // 120 KB
  float* thr16g   = (float*)(ws + ((size_t)34 << 20) + (128 << 10)); // 8 KB

  hipLaunchKernelGGL(prep_wqh, dim3(4096), dim3(256), 0, stream, Wq, Wqh);
  // K = emb @ Wk^T + bk
  hipLaunchKernelGGL(gemm_nt, dim3(HH / TILE, NN / TILE), dim3(256), 0, stream,
                     emb, HH, Wk, HH, Kmat, HH, HH, bk);
  // Z = emb @ Wqh^T
  hipLaunchKernelGGL(gemm_nt, dim3(HH / TILE, NN / TILE), dim3(256), 0, stream,
                     emb, HH, Wqh, HH, Z, HH, HH, (const float*)nullptr);
  // u_i = K_i . Wq[:,H], v_i = K_i . bq
  hipLaunchKernelGGL(uv_k, dim3(NN), dim3(64), 0, stream, Kmat, Wq, bq, u, v);
  hipLaunchKernelGGL(umax_k, dim3(1), dim3(256), 0, stream, u, umax);
  // GT = Z @ K^T + v (v==0 since bq==0 -> bit-identical)
  hipLaunchKernelGGL(gemm_nt, dim3(NN / TILE, NN / TILE), dim3(256), 0, stream,
                     Z, HH, Kmat, HH, GT, NN, HH, v);
  // top-128 candidate lists + packed top-15 tier-1 lists (overlay dead Wqh)
  hipLaunchKernelGGL(prep_cand, dim3(NN), dim3(256), 0, stream, GT, cnd, thr,
                     pc16g, thr16g);
  // pre-warm LLC with cand (2 MB) + thr for tier-2
  hipLaunchKernelGGL(warm_k, dim3(128), dim3(256), 0, stream,
                     (const float*)cnd, NN * KCAND * 2, thr, NN, sink);
  hipLaunchKernelGGL(decode, dim3(1), dim3(64), 0, stream, GT, cnd, thr,
                     pc16g, thr16g, umax, u, demands, cap, depot, out);
}

// Round 2
// 1905.457 us; speedup vs baseline: 1.1557x; 1.1557x over previous
//
#include <hip/hip_runtime.h>
#include <hip/hip_bf16.h>

// BeamDecoder: greedy CVRP-style decode.
// s_i(step) = c*( G[last,i] + (load/cap)*u_i )   (v==0 since bq==0; folded)
//
// R11: R10 failed its prediction (decode 1614us, unchanged). Root cause: the
// tier-2 loads were issued UNCONDITIONALLY each step; thrp[row] (uniform)
// compiles to SMEM which shares lgkmcnt with the tier-1 LDS reads -> the
// compiler's lgkmcnt(0) before consuming s_pc waited ~600cyc for the LLC
// scalar load EVERY step, certified or not. Fix: the certified path is now
// pure LDS+VALU -- zero VMEM/SMEM in it.
//  - tier-2 (128-list) loads moved INSIDE the fallback branch (on-demand,
//    behind a scalar branch; nothing issued when tier-1 certifies).
//  - thr15 & thr128 packed as round-up bf16 halves of one u32 in LDS
//    (round-up keeps the B-test sound: it only makes B more conservative).
//  - s_dd/s_u merged into interleaved float2 s_du[] -> one ds_read_b64
//    gather per candidate instead of two b32 gathers.
//  - tier-1 candidates occupy lanes 0-14 -> DPP reduce is 4 stages +
//    readlane(15) instead of 6 + readlane(63).
// Certified chain ~400cyc (s_pc 120 + s_du 120 + DPP ~80 + scalar ~60);
// bookkeeping (dwin gather, fp32 div) hides under next step's gathers.
// Certification math unchanged from R10 (margin EGM covers the 21-bit
// packing error; B-test vs thr15_ub + lr*umax + 0.5 covers outside nodes;
// rows with top-15 |g|>=128 get thr15=+inf -> always exact path).
// Tier-2 = R9-verbatim exact 128-list eval + B-test vs thr128_ub.
// Tier-3 = R5-verbatim exact full-row scan. Scores exact via deferred pass.

#define NN 2048
#define HH 1024
#define TSTEPS (NN + NN / 8)   // 2304
#define TILE 64
#define KT 16
#define KCAND 128
#define KL 15

// ---------------- pack Wq[:, :H] into ld=1024 buffer ----------------
__global__ __launch_bounds__(256) void prep_wqh(const float* __restrict__ Wq,
                                                float* __restrict__ Wqh) {
  int id = blockIdx.x * 256 + threadIdx.x;
  int r = id >> 10, c = id & 1023;
  Wqh[id] = Wq[r * (HH + 2) + c];
}

// ---------------- NT GEMM: C[M,N] = A[M,K] @ B[N,K]^T (+ bias[n]) ----------------
__global__ __launch_bounds__(256) void gemm_nt(const float* __restrict__ A, int lda,
                                               const float* __restrict__ B, int ldb,
                                               float* __restrict__ C, int ldc,
                                               int K, const float* __restrict__ bias) {
  __shared__ float As[KT][TILE + 4];
  __shared__ float Bs[KT][TILE + 4];
  const int i0 = blockIdx.y * TILE;
  const int j0 = blockIdx.x * TILE;
  const int t = threadIdx.x;
  const int srow = t >> 2, sq = t & 3;
  const int tx = t & 15, ty = t >> 4;
  float acc[4][4] = {};
  for (int k0 = 0; k0 < K; k0 += KT) {
    float4 av = *(const float4*)&A[(size_t)(i0 + srow) * lda + k0 + sq * 4];
    float4 bv = *(const float4*)&B[(size_t)(j0 + srow) * ldb + k0 + sq * 4];
    __syncthreads();
    As[sq * 4 + 0][srow] = av.x; As[sq * 4 + 1][srow] = av.y;
    As[sq * 4 + 2][srow] = av.z; As[sq * 4 + 3][srow] = av.w;
    Bs[sq * 4 + 0][srow] = bv.x; Bs[sq * 4 + 1][srow] = bv.y;
    Bs[sq * 4 + 2][srow] = bv.z; Bs[sq * 4 + 3][srow] = bv.w;
    __syncthreads();
#pragma unroll
    for (int k = 0; k < KT; ++k) {
      float4 a4 = *(const float4*)&As[k][ty * 4];
      float4 b4 = *(const float4*)&Bs[k][tx * 4];
      float a[4] = {a4.x, a4.y, a4.z, a4.w};
      float b[4] = {b4.x, b4.y, b4.z, b4.w};
#pragma unroll
      for (int m = 0; m < 4; ++m)
#pragma unroll
        for (int n = 0; n < 4; ++n) acc[m][n] = fmaf(a[m], b[n], acc[m][n]);
    }
  }
  float bb[4] = {0.f, 0.f, 0.f, 0.f};
  if (bias) {
#pragma unroll
    for (int n = 0; n < 4; ++n) bb[n] = bias[j0 + tx * 4 + n];
  }
#pragma unroll
  for (int m = 0; m < 4; ++m) {
    float4 st = {acc[m][0] + bb[0], acc[m][1] + bb[1], acc[m][2] + bb[2], acc[m][3] + bb[3]};
    *(float4*)&C[(size_t)(i0 + ty * 4 + m) * ldc + j0 + tx * 4] = st;
  }
}

// ---------------- u_i = K_i . Wq[:,H], v_i = K_i . bq  (one wave per row) ---------
__global__ __launch_bounds__(64) void uv_k(const float* __restrict__ Kmat,
                                           const float* __restrict__ Wq,
                                           const float* __restrict__ bq,
                                           float* __restrict__ u, float* __restrict__ v) {
  int i = blockIdx.x;
  int lane = threadIdx.x;
  float su = 0.f, sv = 0.f;
#pragma unroll
  for (int m = 0; m < HH / 64; ++m) {
    int j = lane + 64 * m;
    float kv = Kmat[(size_t)i * HH + j];
    su = fmaf(kv, Wq[(size_t)j * (HH + 2) + HH], su);
    sv = fmaf(kv, bq[j], sv);
  }
#pragma unroll
  for (int off = 32; off; off >>= 1) {
    su += __shfl_down(su, off, 64);
    sv += __shfl_down(sv, off, 64);
  }
  if (lane == 0) { u[i] = su; v[i] = sv; }
}

// ---------------- umax = max |u| ----------------
__global__ __launch_bounds__(256) void umax_k(const float* __restrict__ u,
                                              float* __restrict__ umaxp) {
  __shared__ float sm[256];
  int t = threadIdx.x;
  float m = 0.f;
  for (int i = t; i < NN; i += 256) m = fmaxf(m, fabsf(u[i]));
  sm[t] = m;
  __syncthreads();
  for (int s = 128; s; s >>= 1) {
    if (t < s) sm[t] = fmaxf(sm[t], sm[t + s]);
    __syncthreads();
  }
  if (t == 0) *umaxp = sm[0];
}

// ---------------- per-row exact top-K by g: 4-pass radix-select ----------------
__device__ __forceinline__ unsigned f2key(float f) {
  unsigned x = __float_as_uint(f);
  return x ^ ((x >> 31) ? 0xFFFFFFFFu : 0x80000000u);  // monotonic asc mapping
}
__device__ __forceinline__ float key2f(unsigned k) {
  unsigned x = (k & 0x80000000u) ? (k ^ 0x80000000u) : ~k;
  return __uint_as_float(x);
}
// bf16-style round-UP (toward +inf) of the high 16 float bits. Sound for
// threshold upper bounds: ub16f(x) >= x always (pos: +1ulp16 if low bits set,
// carries into exponent correctly; neg: truncation moves toward zero = up).
__device__ __forceinline__ unsigned ub16(float x) {
  unsigned b = __float_as_uint(x);
  if (x > 0.f && (b & 0xFFFFu)) b += 0x10000u;
  return b >> 16;
}
// Produces: cand[row][0..127] exact top-128 (value,idx); pc16[row][0..14]
// packed top-15 (key&~0x7FF | idx); thrpk[row] = (ub16(thr15)<<16)|ub16(thr128)
// where thr15 is forced to +inf when any of the top-15 has |g|>=128 (disables
// tier-1 for that row so the 21-bit packing error bound holds).
__global__ __launch_bounds__(256) void prep_cand(const float* __restrict__ GT,
                                                 uint2* __restrict__ cand,
                                                 unsigned* __restrict__ pc16,
                                                 unsigned* __restrict__ thrpk) {
  __shared__ float rowv[NN];
  __shared__ int hist[256];
  __shared__ unsigned c128k[KCAND];
  __shared__ int c128i[KCAND];
  __shared__ int s_d, s_need, s_gt, s_eq, s_gt2, s_eq2, s_flag;
  const int row = blockIdx.x, t = threadIdx.x;
  for (int i = t; i < NN; i += 256) rowv[i] = GT[(size_t)row * NN + i];
  __syncthreads();
  unsigned prefix = 0;
  int need = KCAND;
  for (int pass = 0; pass < 4; ++pass) {
    hist[t] = 0;
    __syncthreads();
    const int shift = 24 - 8 * pass;
    for (int i = t; i < NN; i += 256) {
      unsigned k = f2key(rowv[i]);
      if (pass == 0 || (k >> (shift + 8)) == (prefix >> (shift + 8)))
        atomicAdd(&hist[(k >> shift) & 0xFF], 1);
    }
    __syncthreads();
    if (t == 0) {
      int cum = 0, d = 255;
      for (; d > 0; --d) {
        if (cum + hist[d] >= need) break;
        cum += hist[d];
      }
      s_d = d;
      s_need = need - cum;
    }
    __syncthreads();
    prefix |= ((unsigned)s_d) << shift;
    need = s_need;
    __syncthreads();
  }
  const unsigned thrk = prefix;  // exact KCAND-th largest key
  if (t == 0) { s_gt = 0; s_eq = 0; }
  __syncthreads();
  for (int i = t; i < NN; i += 256) {
    unsigned k = f2key(rowv[i]);
    if (k > thrk) {
      int p = atomicAdd(&s_gt, 1);
      cand[(size_t)row * KCAND + p] = make_uint2(__float_as_uint(rowv[i]), (unsigned)i);
      c128k[p] = k;
      c128i[p] = i;
    }
  }
  __syncthreads();
  const int cgt = s_gt;
  for (int i = t; i < NN; i += 256) {
    if (f2key(rowv[i]) == thrk) {
      int p = atomicAdd(&s_eq, 1);
      if (p < KCAND - cgt) {
        cand[(size_t)row * KCAND + cgt + p] = make_uint2(__float_as_uint(rowv[i]), (unsigned)i);
        c128k[cgt + p] = thrk;
        c128i[cgt + p] = i;
      }
    }
  }
  __syncthreads();
  // ---- exact 15th-largest among the 128 keys (== row's top-15 multiset)
  unsigned pfx2 = 0;
  need = KL;
  for (int pass = 0; pass < 4; ++pass) {
    hist[t] = 0;
    __syncthreads();
    const int shift = 24 - 8 * pass;
    for (int i = t; i < KCAND; i += 256) {
      unsigned k = c128k[i];
      if (pass == 0 || (k >> (shift + 8)) == (pfx2 >> (shift + 8)))
        atomicAdd(&hist[(k >> shift) & 0xFF], 1);
    }
    __syncthreads();
    if (t == 0) {
      int cum = 0, d = 255;
      for (; d > 0; --d) {
        if (cum + hist[d] >= need) break;
        cum += hist[d];
      }
      s_d = d;
      s_need = need - cum;
    }
    __syncthreads();
    pfx2 |= ((unsigned)s_d) << shift;
    need = s_need;
    __syncthreads();
  }
  const unsigned thrk15 = pfx2;
  if (t == 0) { s_gt2 = 0; s_eq2 = 0; s_flag = 0; }
  __syncthreads();
  for (int i = t; i < KCAND; i += 256) {
    if (c128k[i] > thrk15) {
      int p = atomicAdd(&s_gt2, 1);
      pc16[(size_t)row * KL + p] = (c128k[i] & 0xFFFFF800u) | (unsigned)c128i[i];
      if (fabsf(key2f(c128k[i])) >= 128.0f) s_flag = 1;
    }
  }
  __syncthreads();
  const int cgt2 = s_gt2;
  for (int i = t; i < KCAND; i += 256) {
    if (c128k[i] == thrk15) {
      int p = atomicAdd(&s_eq2, 1);
      if (p < KL - cgt2)
        pc16[(size_t)row * KL + cgt2 + p] = (thrk15 & 0xFFFFF800u) | (unsigned)c128i[i];
    }
  }
  if (t == 0 && fabsf(key2f(thrk15)) >= 128.0f) s_flag = 1;
  __syncthreads();
  if (t == 0) {
    float t15 = s_flag ? __builtin_inff() : key2f(thrk15);
    thrpk[row] = (ub16(t15) << 16) | ub16(key2f(thrk));
  }
}

// ---------------- LLC pre-warm for the (rare) tier-2 fallback lists --------------
__global__ __launch_bounds__(256) void warm_k(const float* __restrict__ a, int n,
                                              float* __restrict__ sink) {
  float s = 0.f;
  const float4* a4 = (const float4*)a;
  for (int i = threadIdx.x; i < n / 4; i += 256) {
    float4 x = a4[i];
    s += x.x + x.y + x.z + x.w;
  }
  if (s == 1.2345e-30f) sink[blockIdx.x] = s;  // never true; keeps loads alive
}

// DPP merge of (bv,bi): max value, smallest index on ties. Invalid lanes get
// (-inf, INT_MAX).
#define DPP_MERGE2(CTRL)                                                      \
  {                                                                           \
    int ovb = __builtin_amdgcn_update_dpp(                                    \
        (int)0xFF800000, __float_as_int(bv), (CTRL), 0xf, 0xf, false);        \
    int oib = __builtin_amdgcn_update_dpp(                                    \
        0x7fffffff, bi, (CTRL), 0xf, 0xf, false);                             \
    float ov = __int_as_float(ovb);                                           \
    if (ov > bv || (ov == bv && oib < bi)) { bv = ov; bi = oib; }             \
  }

// DPP top-2 merge: (bv1,bi1) = max with min-idx ties; bv2 = runner-up VALUE
// of the union (merge of two top-2 sets {a1,a2},{b1,b2} is
// top2{a1,b1,max(a2,b2)} -- lose=min(a1,b1) supplies the loser).
#define DPP_TOP2(CTRL)                                                        \
  {                                                                           \
    int ovb = __builtin_amdgcn_update_dpp(                                    \
        (int)0xFF800000, __float_as_int(bv1), (CTRL), 0xf, 0xf, false);       \
    int oib = __builtin_amdgcn_update_dpp(                                    \
        0x7fffffff, bi1, (CTRL), 0xf, 0xf, false);                            \
    int ov2b = __builtin_amdgcn_update_dpp(                                   \
        (int)0xFF800000, __float_as_int(bv2), (CTRL), 0xf, 0xf, false);       \
    float ov1 = __int_as_float(ovb);                                          \
    float ov2 = __int_as_float(ov2b);                                         \
    float lose = fminf(bv1, ov1);                                             \
    if (ov1 > bv1 || (ov1 == bv1 && oib < bi1)) { bv1 = ov1; bi1 = oib; }     \
    bv2 = fmaxf(fmaxf(bv2, ov2), lose);                                       \
  }

// ---------------- sequential decode: ONE wave ------------------------------------
// Certified path is pure LDS+VALU (no VMEM/SMEM). Fallbacks load on demand.
__global__ __launch_bounds__(64, 1) void decode(const float* __restrict__ GT,
                                                const uint2* __restrict__ cand,
                                                const unsigned* __restrict__ pc16,
                                                const unsigned* __restrict__ thrpkg,
                                                const float* __restrict__ umaxp,
                                                const float* __restrict__ u,
                                                const float* __restrict__ demands,
                                                const int* __restrict__ capp,
                                                const int* __restrict__ depotp,
                                                float* __restrict__ out) {
  __shared__ __align__(16) unsigned s_pc[NN * KL + 64];  // packed tier-1 lists (+pad)
  __shared__ __align__(16) float2 s_du[NN];              // (.x=demand|+inf, .y=u_i)
  __shared__ __align__(16) unsigned s_thr[NN];           // packed ub16(thr15)|ub16(thr128)
  __shared__ __align__(16) float s_lr[TSTEPS];           // lr per step; -1 => score 0
  __shared__ __align__(16) unsigned short s_tour[TSTEPS + 2];

  const int lane = threadIdx.x;
  const int depot = *depotp;
  const float capf = (float)(*capp);
  const float umaxv = *umaxp;
  const float INF = __builtin_inff();
  const float NEGINF = -INF;
  const float C0 = 0.015625f;   // ALPHA / sqrt(HID), exact power of two
  const float MARGIN = 0.5f;    // >> any fp32 rounding in the bound
  const float EGM = 0.0625f;    // > 2x packing error (0.0156 @ |g|<128) + rounding
  float* sduf = (float*)s_du;

  for (int i = lane; i < NN; i += 64) {
    s_du[i] = make_float2(demands[i], u[i]);
    s_thr[i] = thrpkg[i];
  }
  {
    const uint4* p4 = (const uint4*)pc16;
    uint4* q4 = (uint4*)s_pc;
    for (int i = lane; i < NN * KL / 4; i += 64) q4[i] = p4[i];  // 7680 words/4
  }
  if (lane == 0) {
    sduf[2 * depot] = INF;  // depot starts visited
    s_tour[0] = (unsigned short)depot;
  }
  // single wave: per-wave LDS ordering suffices; no barrier needed

  int done = 0, ntaken = 0, lasts = depot;
  float load = capf;
  float lr = load / capf;  // same fp32 division as reference
  int step = 0;
  const int lcl = (lane < KL) ? lane : (KL - 1);  // lanes >=15 broadcast-read entry 14

  for (; step < TSTEPS; ++step) {
    const int row = lasts;
    // ---- tier-1: 15 packed candidates, lanes 0-14 (pure LDS + VALU)
    unsigned pw = s_pc[row * KL + lcl];
    unsigned pk = s_thr[row];
    int i1x = (int)(pw & 0x7FFu);
    float g1 = key2f(pw & 0xFFFFF800u);  // ghat <= g <= ghat + 0.0156
    float2 du1 = s_du[i1x];              // one ds_read_b64
    float t1 = fmaf(du1.y, lr, g1);
    bool act = (lane < KL) && (du1.x <= load);
    float bv1 = act ? t1 : NEGINF;
    int bi1 = act ? i1x : 0x7fffffff;
    float bv2 = NEGINF;
    DPP_TOP2(0x111); DPP_TOP2(0x112); DPP_TOP2(0x114); DPP_TOP2(0x118);
    float rv1 = __int_as_float(__builtin_amdgcn_readlane(__float_as_int(bv1), 15));
    int ri1 = __builtin_amdgcn_readlane(bi1, 15);
    float rv2 = __int_as_float(__builtin_amdgcn_readlane(__float_as_int(bv2), 15));
    float thr1 = __uint_as_float(pk & 0xFFFF0000u);  // ub(thr15); +inf if flagged
    const float B1 = fmaf(lr, umaxv, thr1) + MARGIN;
    int take, nxt;
    if (rv1 > B1 && rv1 > rv2 + EGM) {
      // certified: true t_w >= rv1 > rv2+EGM >= true t of any other in-list
      // candidate (packing err < EGM/2 each side), and rv1 > B1 beats every
      // node with g <= thr15 (all nodes outside the 15). Unique argmax.
      take = 1; nxt = ri1;
    } else {
      // ---- tier-2: on-demand exact eval of the 128-candidate list
      uint4 cc = ((const uint4*)(cand + (size_t)row * KCAND))[lane];
      float bv = NEGINF;
      int bi = 0x7fffffff;
      {
        float ga = __uint_as_float(cc.x); int ia = (int)cc.y;
        float gb = __uint_as_float(cc.z); int ib = (int)cc.w;
        float2 da = s_du[ia];
        float2 db = s_du[ib];
        float ta = fmaf(da.y, lr, ga);
        float tb = fmaf(db.y, lr, gb);
        if ((da.x <= load) && (ta > bv || (ta == bv && ia < bi))) { bv = ta; bi = ia; }
        if ((db.x <= load) && (tb > bv || (tb == bv && ib < bi))) { bv = tb; bi = ib; }
      }
      DPP_MERGE2(0x111); DPP_MERGE2(0x112); DPP_MERGE2(0x114);
      DPP_MERGE2(0x118); DPP_MERGE2(0x142); DPP_MERGE2(0x143);
      float rbv = __int_as_float(__builtin_amdgcn_readlane(__float_as_int(bv), 63));
      int rbi = __builtin_amdgcn_readlane(bi, 63);
      float thr2 = __uint_as_float(pk << 16);  // ub(thr128)
      const float B2 = fmaf(lr, umaxv, thr2) + MARGIN;
      if (rbv > B2) {
        take = 1; nxt = rbi;
      } else {
        // ---- tier-3: R5-verbatim exact full-row scan
        const float4* rowp = (const float4*)(GT + (size_t)row * NN);
        const float4* du4 = (const float4*)s_du;
        float fv = NEGINF;
        int fi = NN;
#pragma unroll
        for (int r = 0; r < 8; ++r) {
          float4 g4 = rowp[r * 64 + lane];
          float4 pA = du4[(r * 64 + lane) * 2];      // d0,u0,d1,u1
          float4 pB = du4[(r * 64 + lane) * 2 + 1];  // d2,u2,d3,u3
          float gl[4] = {g4.x, g4.y, g4.z, g4.w};
          float dl[4] = {pA.x, pA.z, pB.x, pB.z};
          float ul[4] = {pA.y, pA.w, pB.y, pB.w};
          float cv = NEGINF;
          int cj = 0;
#pragma unroll
          for (int j = 0; j < 4; ++j) {
            float tt = fmaf(ul[j], lr, gl[j]);
            bool feas = (dl[j] <= load);
            if (feas && tt > cv) { cv = tt; cj = j; }
          }
          if (cv > fv) { fv = cv; fi = 4 * (r * 64 + lane) + cj; }  // asc r: first-max
        }
        float bv = fv;
        int bi = fi;
        DPP_MERGE2(0x111); DPP_MERGE2(0x112); DPP_MERGE2(0x114);
        DPP_MERGE2(0x118); DPP_MERGE2(0x142); DPP_MERGE2(0x143);
        float fbv = __int_as_float(__builtin_amdgcn_readlane(__float_as_int(bv), 63));
        int fbi = __builtin_amdgcn_readlane(bi, 63);
        take = (fbv > NEGINF) ? 1 : 0;
        nxt = take ? fbi : depot;
      }
    }

    // ---- state update + LDS-buffered outputs (identical fp ops to ref)
    if (lane == 0) {
      s_tour[1 + step] = (unsigned short)nxt;
      s_lr[step] = take ? lr : -1.0f;
    }
    if (take) {
      float dwin = s_du[nxt].x;  // raw demand: feasible => not yet INF
      load = load - dwin;
      ntaken++;
      if (lane == 0) sduf[2 * nxt] = INF;
    } else {
      load = capf;
      if (ntaken == NN - 1) done = 1;
    }
    lasts = nxt;
    lr = load / capf;  // same fp32 division as reference
    if (done) { ++step; break; }
  }

  // ref emits (depot, 0) forever once done
  for (int q = step + lane; q < TSTEPS; q += 64) {
    s_tour[1 + q] = (unsigned short)depot;
    s_lr[q] = -1.0f;
  }
  // ---- flush tour; compute scores exactly in a parallel deferred pass
  for (int i = lane; i <= TSTEPS; i += 64) out[i] = (float)s_tour[i];
  for (int s = lane; s < TSTEPS; s += 64) {
    float lrs = s_lr[s];
    float sc = 0.0f;
    if (lrs >= 0.0f) {
      int lastI = (int)s_tour[s];
      int biI = (int)s_tour[s + 1];
      float g = GT[(size_t)lastI * NN + biI];
      sc = fmaf(s_du[biI].y, lrs, g) * C0;  // identical expression to R3-R10
    }
    out[1 + TSTEPS + s] = sc;
  }
}

extern "C" void kernel_launch(void* const* d_in, const int* in_sizes, int n_in,
                              void* d_out, int out_size, void* d_ws, size_t ws_size,
                              hipStream_t stream) {
  const float* emb     = (const float*)d_in[0];  // [N, H]
  const float* demands = (const float*)d_in[1];  // [N]
  const float* Wq      = (const float*)d_in[2];  // [H, H+2]
  const float* bq      = (const float*)d_in[3];  // [H]
  const float* Wk      = (const float*)d_in[4];  // [H, H]
  const float* bk      = (const float*)d_in[5];  // [H]
  const int* cap       = (const int*)d_in[6];
  const int* depot     = (const int*)d_in[7];
  float* out           = (float*)d_out;          // 2305 tour + 2304 scores, fp32

  char* ws = (char*)d_ws;
  float* Kmat = (float*)(ws);                         // 8 MB  [N,H]
  float* Z    = (float*)(ws + ((size_t)8 << 20));     // 8 MB  [N,H]
  float* GT   = (float*)(ws + ((size_t)16 << 20));    // 16 MB [N,N] row=last, +v
  float* Wqh  = (float*)(ws + ((size_t)32 << 20));    // 4 MB  [H,H]; later = cand+pc16
  float* u    = (float*)(ws + ((size_t)36 << 20));    // 8 KB
  float* v    = (float*)(ws + ((size_t)36 << 20) + 8192);
  unsigned* thrpkg = (unsigned*)(ws + ((size_t)36 << 20) + 16384);  // 8 KB packed thr
  float* umax = (float*)(ws + ((size_t)36 << 20) + 24576);
  float* sink = (float*)(ws + ((size_t)36 << 20) + 32768);  // warm sink (unused)
  uint2* cnd  = (uint2*)Wqh;  // 2 MB = 2048*128*8 B; Wqh dead after Z GEMM
  unsigned* pc16g = (unsigned*)(ws + ((size_t)34 << 20));   // 120 KB packed top-15

  hipLaunchKernelGGL(prep_wqh, dim3(4096), dim3(256), 0, stream, Wq, Wqh);
  // K = emb @ Wk^T + bk
  hipLaunchKernelGGL(gemm_nt, dim3(HH / TILE, NN / TILE), dim3(256), 0, stream,
                     emb, HH, Wk, HH, Kmat, HH, HH, bk);
  // Z = emb @ Wqh^T
  hipLaunchKernelGGL(gemm_nt, dim3(HH / TILE, NN / TILE), dim3(256), 0, stream,
                     emb, HH, Wqh, HH, Z, HH, HH, (const float*)nullptr);
  // u_i = K_i . Wq[:,H], v_i = K_i . bq
  hipLaunchKernelGGL(uv_k, dim3(NN), dim3(64), 0, stream, Kmat, Wq, bq, u, v);
  hipLaunchKernelGGL(umax_k, dim3(1), dim3(256), 0, stream, u, umax);
  // GT = Z @ K^T + v (v==0 since bq==0 -> bit-identical)
  hipLaunchKernelGGL(gemm_nt, dim3(NN / TILE, NN / TILE), dim3(256), 0, stream,
                     Z, HH, Kmat, HH, GT, NN, HH, v);
  // top-128 candidate lists + packed top-15 tier-1 lists (overlay dead Wqh)
  hipLaunchKernelGGL(prep_cand, dim3(NN), dim3(256), 0, stream, GT, cnd,
                     pc16g, thrpkg);
  // pre-warm LLC with cand (2 MB) for the on-demand tier-2 fallback
  hipLaunchKernelGGL(warm_k, dim3(128), dim3(256), 0, stream,
                     (const float*)cnd, NN * KCAND * 2, sink);
  hipLaunchKernelGGL(decode, dim3(1), dim3(64), 0, stream, GT, cnd,
                     pc16g, thrpkg, umax, u, demands, cap, depot, out);
}